// Round 1
// baseline (2561.089 us; speedup 1.0000x reference)
//
#include <hip/hip_runtime.h>
#include <hip/hip_bf16.h>
#include <math.h>

#define VV 50000
#define EE 300
#define HD 256
#define BB 256
#define TT 64
#define NEGV -1e9f

// ws layout (floats):
//   H: [2 buf][2 dir][B][HD]   offset 0,        262144 floats
//   C: [2 dir][B][HD]          offset 262144,   131072 floats
// total 393216 floats = 1.5 MB

__global__ __launch_bounds__(256) void init_kernel(float* __restrict__ ws,
                                                   float* __restrict__ out) {
  int idx = blockIdx.x * 256 + threadIdx.x;
  if (idx < (2 * 2 * BB * HD + 2 * BB * HD)) ws[idx] = 0.f;
  if (idx < BB * 2 * HD) out[idx] = NEGV;
}

__global__ __launch_bounds__(256) void step_kernel(
    const int* __restrict__ tok, const int* __restrict__ lens,
    const float* __restrict__ emb,
    const float* __restrict__ wih_f, const float* __restrict__ whh_f,
    const float* __restrict__ bias_f,
    const float* __restrict__ wih_b, const float* __restrict__ whh_b,
    const float* __restrict__ bias_b,
    float* __restrict__ ws, float* __restrict__ out, int s) {
  const int tid = threadIdx.x;
  const int jt = blockIdx.x;   // 0..7  (32 hidden units each)
  const int bt = blockIdx.y;   // 0..15 (16 batch rows each)
  const int dir = blockIdx.z;  // 0..1
  const int j0 = jt * 32;
  const int b0g = bt * 16;
  const int t = (dir == 0) ? s : (TT - 1 - s);

  const float* Wih = dir ? wih_b : wih_f;
  const float* Whh = dir ? whh_b : whh_f;
  const float* bias = dir ? bias_b : bias_f;

  float* Hbuf = ws;
  float* Cbuf = ws + 2 * 2 * BB * HD;
  const float* hcur = Hbuf + (size_t)((s & 1) * 2 + dir) * BB * HD;
  float* hnxt = Hbuf + (size_t)((((s + 1) & 1) * 2) + dir) * BB * HD;
  float* cbuf = Cbuf + (size_t)dir * BB * HD;

  __shared__ float a_sm[16][64];
  __shared__ float w_sm[64][132];
  __shared__ float z_sm[16][132];

  const int cg = tid & 31;  // col group: 4 consecutive tile-cols
  const int bg = tid >> 5;  // row group: 2 consecutive batch rows
  float acc[2][4] = {{0.f, 0.f, 0.f, 0.f}, {0.f, 0.f, 0.f, 0.f}};

  for (int phase = 0; phase < 2; ++phase) {
    const float* W = phase ? Whh : Wih;
    const int K = phase ? HD : EE;
    for (int k0 = 0; k0 < K; k0 += 64) {
      const int klen = (K - k0) < 64 ? (K - k0) : 64;
      // ---- load A tile: 16 rows x klen (float4 per thread) ----
      {
        int bl = tid >> 4, kk4 = tid & 15;
        if (kk4 * 4 < klen) {
          const float* src;
          if (phase == 0) {
            int tk = tok[(b0g + bl) * TT + t];
            src = emb + (size_t)tk * EE + k0 + kk4 * 4;
          } else {
            src = hcur + (size_t)(b0g + bl) * HD + k0 + kk4 * 4;
          }
          float4 v = *(const float4*)src;
          *(float4*)&a_sm[bl][kk4 * 4] = v;
        }
      }
      // ---- load W tile: 128 cols x klen, transposed into w_sm[k][col] ----
      for (int i = 0; i < 8; ++i) {
        int e = i * 256 + tid;
        int col = e >> 4, kk4 = e & 15;
        if (kk4 * 4 < klen) {
          int gcol = ((col >> 5) * HD) + j0 + (col & 31);
          float4 v = *(const float4*)(W + (size_t)gcol * K + k0 + kk4 * 4);
          w_sm[kk4 * 4 + 0][col] = v.x;
          w_sm[kk4 * 4 + 1][col] = v.y;
          w_sm[kk4 * 4 + 2][col] = v.z;
          w_sm[kk4 * 4 + 3][col] = v.w;
        }
      }
      __syncthreads();
      for (int k = 0; k < klen; ++k) {
        float a0 = a_sm[bg * 2 + 0][k];
        float a1 = a_sm[bg * 2 + 1][k];
        float4 w = *(const float4*)&w_sm[k][cg * 4];
        acc[0][0] += a0 * w.x; acc[0][1] += a0 * w.y;
        acc[0][2] += a0 * w.z; acc[0][3] += a0 * w.w;
        acc[1][0] += a1 * w.x; acc[1][1] += a1 * w.y;
        acc[1][2] += a1 * w.z; acc[1][3] += a1 * w.w;
      }
      __syncthreads();
    }
  }

  // ---- write z tile to LDS ----
  *(float4*)&z_sm[bg * 2 + 0][cg * 4] =
      make_float4(acc[0][0], acc[0][1], acc[0][2], acc[0][3]);
  *(float4*)&z_sm[bg * 2 + 1][cg * 4] =
      make_float4(acc[1][0], acc[1][1], acc[1][2], acc[1][3]);
  __syncthreads();

  // ---- gate phase: 512 (b,j) pairs, 2 per thread ----
  for (int pi = 0; pi < 2; ++pi) {
    int p = pi * 256 + tid;
    int bl = p >> 5, jl = p & 31;
    int bglob = b0g + bl;
    int jglob = j0 + jl;
    bool valid = t < lens[bglob];
    float h_old = hcur[(size_t)bglob * HD + jglob];
    float h_out = h_old;
    if (valid) {
      float zi = z_sm[bl][0 + jl]  + bias[0 * HD + jglob];
      float zf = z_sm[bl][32 + jl] + bias[1 * HD + jglob];
      float zg = z_sm[bl][64 + jl] + bias[2 * HD + jglob];
      float zo = z_sm[bl][96 + jl] + bias[3 * HD + jglob];
      float ig = 1.f / (1.f + expf(-zi));
      float fg = 1.f / (1.f + expf(-zf));
      float gg = tanhf(zg);
      float og = 1.f / (1.f + expf(-zo));
      float c_old = cbuf[(size_t)bglob * HD + jglob];
      float c_new = fg * c_old + ig * gg;
      float h_new = og * tanhf(c_new);
      cbuf[(size_t)bglob * HD + jglob] = c_new;
      h_out = h_new;
      float* op = out + (size_t)bglob * (2 * HD) + dir * HD + jglob;
      *op = fmaxf(*op, h_new);
    }
    hnxt[(size_t)bglob * HD + jglob] = h_out;
  }
}

extern "C" void kernel_launch(void* const* d_in, const int* in_sizes, int n_in,
                              void* d_out, int out_size, void* d_ws,
                              size_t ws_size, hipStream_t stream) {
  const int* tok = (const int*)d_in[0];
  const int* lens = (const int*)d_in[1];
  const float* emb = (const float*)d_in[2];
  const float* wih_f = (const float*)d_in[3];
  const float* whh_f = (const float*)d_in[4];
  const float* b_f = (const float*)d_in[5];
  const float* wih_b = (const float*)d_in[6];
  const float* whh_b = (const float*)d_in[7];
  const float* b_b = (const float*)d_in[8];
  float* out = (float*)d_out;
  float* ws = (float*)d_ws;

  hipLaunchKernelGGL(init_kernel, dim3(1536), dim3(256), 0, stream, ws, out);
  for (int s = 0; s < TT; ++s) {
    hipLaunchKernelGGL(step_kernel, dim3(8, 16, 2), dim3(256), 0, stream, tok,
                       lens, emb, wih_f, whh_f, b_f, wih_b, whh_b, b_b, ws, out,
                       s);
  }
}

// Round 2
// 2467.556 us; speedup vs baseline: 1.0379x; 1.0379x over previous
//
#include <hip/hip_runtime.h>
#include <hip/hip_bf16.h>
#include <math.h>

#define VV 50000
#define EE 300
#define HD 256
#define BB 256
#define TT 64
#define NEGV -1e9f

// ws layout (floats):
#define OFF_H   0          // [2 buf][2 dir][B][HD]      262144
#define OFF_C   262144     // [2 dir][B][HD]             131072
#define OFF_B2  393216     // [2 dir][1024] gate-interleaved bias   2048
#define OFF_WHH 395264     // [2 dir][256 k][1024 jg]    524288
#define OFF_WIH 919552     // [320 k][2 dir * 1024 jg]   655360 (rows 300..319 zero)
#define OFF_ZX  1574912    // [(b*64+t)][2048]           33554432
#define WS_FULL_BYTES (35129344ULL * 4ULL)

__device__ __forceinline__ float sigf(float x) { return 1.f / (1.f + expf(-x)); }

// ---------------- init: zero H/C, out=-1e9, build gate-interleaved bias ----
__global__ __launch_bounds__(256) void init_kernel(float* __restrict__ ws,
                                                   float* __restrict__ out,
                                                   const float* __restrict__ bf,
                                                   const float* __restrict__ bb,
                                                   int full) {
  int idx = blockIdx.x * 256 + threadIdx.x;
  if (idx < 393216) ws[idx] = 0.f;
  if (idx < BB * 2 * HD) out[idx] = NEGV;
  if (full && idx < 2048) {
    int dir = idx >> 10, jg = idx & 1023, j = jg >> 2, g = jg & 3;
    ws[OFF_B2 + idx] = (dir ? bb : bf)[g * HD + j];
  }
}

// ---------------- prep: transpose W_hh -> [dir][k][j*4+g] ------------------
__global__ __launch_bounds__(256) void prep_whh(const float* __restrict__ wf,
                                                const float* __restrict__ wb,
                                                float* __restrict__ ws) {
  int o = blockIdx.x * 256 + threadIdx.x;  // < 524288
  int dir = o >> 18, r = o & 262143, k = r >> 10, jg = r & 1023;
  int j = jg >> 2, g = jg & 3;
  const float* W = dir ? wb : wf;
  ws[OFF_WHH + o] = W[(size_t)((g << 8) + j) * HD + k];
}

// ---------------- prep: transpose W_ih -> [k(320)][dir*1024 + j*4+g] -------
__global__ __launch_bounds__(256) void prep_wih(const float* __restrict__ wf,
                                                const float* __restrict__ wb,
                                                float* __restrict__ ws) {
  int o = blockIdx.x * 256 + threadIdx.x;  // < 655360
  int k = o >> 11, r = o & 2047, dir = r >> 10, jg = r & 1023;
  int j = jg >> 2, g = jg & 3;
  float v = 0.f;
  if (k < EE) {
    const float* W = dir ? wb : wf;
    v = W[(size_t)((g << 8) + j) * EE + k];
  }
  ws[OFF_WIH + o] = v;
}

// ---------------- Zx = X @ Wih^T for all (b,t): M=16384 N=2048 K=300 -------
__global__ __launch_bounds__(256) void zx_gemm(const int* __restrict__ tok,
                                               const float* __restrict__ emb,
                                               float* __restrict__ ws) {
  __shared__ float a_sm[64][68];
  __shared__ float b_sm[64][132];
  const int tid = threadIdx.x;
  const int m0 = blockIdx.x * 64;   // m = b*64+t, matches tok[b][t] flat
  const int n0 = blockIdx.y * 128;  // n = dir*1024 + j*4+g
  const float* wih = ws + OFF_WIH;
  float* zx = ws + OFF_ZX;

  float acc[4][8];
#pragma unroll
  for (int i = 0; i < 4; ++i)
#pragma unroll
    for (int jj = 0; jj < 8; ++jj) acc[i][jj] = 0.f;

  const int arow = tid >> 2, aq = tid & 3;
  const int tokv = tok[m0 + arow];
  const float* er = emb + (size_t)tokv * EE;
  const int mg = (tid >> 4) * 4;  // 4 m rows per thread
  const int ng = (tid & 15) * 8;  // 8 n cols per thread

  for (int kc = 0; kc < 5; ++kc) {
    const int k0 = kc * 64;
    // A tile: 64 rows x 64 k (zero-padded past K=300)
#pragma unroll
    for (int i = 0; i < 4; ++i) {
      int c = aq * 16 + i * 4;
      float4 v = make_float4(0.f, 0.f, 0.f, 0.f);
      if (k0 + c + 3 < EE) v = *(const float4*)(er + k0 + c);
      *(float4*)&a_sm[arow][c] = v;
    }
    // B tile: 64 k x 128 n (wih_t rows >=300 are zero)
    const float* bs = wih + (size_t)(k0 + arow) * 2048 + n0;
#pragma unroll
    for (int i = 0; i < 8; ++i) {
      int n = aq * 32 + i * 4;
      *(float4*)&b_sm[arow][n] = *(const float4*)(bs + n);
    }
    __syncthreads();
#pragma unroll 8
    for (int k = 0; k < 64; ++k) {
      float a[4];
#pragma unroll
      for (int i = 0; i < 4; ++i) a[i] = a_sm[mg + i][k];
      float4 b0 = *(const float4*)&b_sm[k][ng];
      float4 b1 = *(const float4*)&b_sm[k][ng + 4];
#pragma unroll
      for (int i = 0; i < 4; ++i) {
        acc[i][0] += a[i] * b0.x; acc[i][1] += a[i] * b0.y;
        acc[i][2] += a[i] * b0.z; acc[i][3] += a[i] * b0.w;
        acc[i][4] += a[i] * b1.x; acc[i][5] += a[i] * b1.y;
        acc[i][6] += a[i] * b1.z; acc[i][7] += a[i] * b1.w;
      }
    }
    __syncthreads();
  }
#pragma unroll
  for (int i = 0; i < 4; ++i) {
    float* dst = zx + (size_t)(m0 + mg + i) * 2048 + n0 + ng;
    *(float4*)dst = make_float4(acc[i][0], acc[i][1], acc[i][2], acc[i][3]);
    *(float4*)(dst + 4) = make_float4(acc[i][4], acc[i][5], acc[i][6], acc[i][7]);
  }
}

// ---------------- recurrent step: z = Zx[t] + h @ Whh^T, gates, max --------
__global__ __launch_bounds__(256) void step_kernel(const int* __restrict__ lens,
                                                   float* __restrict__ ws,
                                                   float* __restrict__ out,
                                                   int s) {
  const int tid = threadIdx.x;
  const int jt = blockIdx.x;   // 0..3  (64 j each)
  const int bt = blockIdx.y;   // 0..31 (8 b each)
  const int dir = blockIdx.z;  // 0..1
  const int t = dir ? (TT - 1 - s) : s;
  const int jl = tid & 63;
  const int bl = (tid >> 6) * 2;  // rows bl, bl+1 of the 8
  const int b0 = bt * 8;

  const float* hcur = ws + OFF_H + (size_t)((s & 1) * 2 + dir) * BB * HD;
  float* hnxt = ws + OFF_H + (size_t)(((s + 1) & 1) * 2 + dir) * BB * HD;
  float* cb = ws + OFF_C + (size_t)dir * BB * HD;
  const float* whh = ws + OFF_WHH + (size_t)dir * 256 * 1024;
  const float* zx = ws + OFF_ZX;
  const float* b2 = ws + OFF_B2 + dir * 1024;

  __shared__ float h_sm[8][256];
  __shared__ float w_sm[32][260];

  const int brow0 = b0 + bl, brow1 = b0 + bl + 1;
  const int j = jt * 64 + jl;

  // issue independent loads early
  const int len0 = lens[brow0], len1 = lens[brow1];
  const float4 zx0 = *(const float4*)(zx + ((size_t)brow0 * TT + t) * 2048 + dir * 1024 + jt * 256 + jl * 4);
  const float4 zx1 = *(const float4*)(zx + ((size_t)brow1 * TT + t) * 2048 + dir * 1024 + jt * 256 + jl * 4);
  const float4 bias = *(const float4*)(b2 + jt * 256 + jl * 4);
  const float c0_old = cb[(size_t)brow0 * HD + j];
  const float c1_old = cb[(size_t)brow1 * HD + j];

  // stage h tile (8 b-rows x 256)
  {
    int row = tid >> 5, c = (tid & 31) * 4;
    const float* src = hcur + (size_t)(b0 + row) * HD;
    *(float4*)&h_sm[row][c] = *(const float4*)(src + c);
    *(float4*)&h_sm[row][c + 128] = *(const float4*)(src + c + 128);
  }

  float4 acc0 = make_float4(0.f, 0.f, 0.f, 0.f);
  float4 acc1 = make_float4(0.f, 0.f, 0.f, 0.f);
  const int wk = tid >> 3;  // 0..31 (k row)
  const int wq = tid & 7;   // 0..7

  // prefetch W chunk 0
  float4 wreg[8];
  {
    const float* wsrc = whh + (size_t)wk * 1024 + jt * 256;
#pragma unroll
    for (int i = 0; i < 8; ++i) wreg[i] = *(const float4*)(wsrc + wq * 4 + i * 32);
  }

  for (int kc = 0; kc < 8; ++kc) {
    __syncthreads();  // prev compute done (covers h_sm store on first iter)
#pragma unroll
    for (int i = 0; i < 8; ++i) *(float4*)&w_sm[wk][wq * 4 + i * 32] = wreg[i];
    __syncthreads();
    if (kc < 7) {
      const float* wsrc = whh + (size_t)((kc + 1) * 32 + wk) * 1024 + jt * 256;
#pragma unroll
      for (int i = 0; i < 8; ++i) wreg[i] = *(const float4*)(wsrc + wq * 4 + i * 32);
    }
    const int k0 = kc * 32;
#pragma unroll
    for (int k = 0; k < 32; ++k) {
      float h0 = h_sm[bl][k0 + k];
      float h1 = h_sm[bl + 1][k0 + k];
      float4 w = *(const float4*)&w_sm[k][jl * 4];
      acc0.x += h0 * w.x; acc0.y += h0 * w.y; acc0.z += h0 * w.z; acc0.w += h0 * w.w;
      acc1.x += h1 * w.x; acc1.y += h1 * w.y; acc1.z += h1 * w.z; acc1.w += h1 * w.w;
    }
  }

  // gates, fully in-register (x=i, y=f, z=g, w=o)
  const float h0_old = h_sm[bl][j];
  const float h1_old = h_sm[bl + 1][j];
  {
    bool v = t < len0;
    float h_out = h0_old;
    if (v) {
      float ig = sigf(acc0.x + zx0.x + bias.x);
      float fg = sigf(acc0.y + zx0.y + bias.y);
      float gg = tanhf(acc0.z + zx0.z + bias.z);
      float og = sigf(acc0.w + zx0.w + bias.w);
      float cn = fg * c0_old + ig * gg;
      float hn = og * tanhf(cn);
      cb[(size_t)brow0 * HD + j] = cn;
      h_out = hn;
      float* op = out + (size_t)brow0 * (2 * HD) + dir * HD + j;
      *op = fmaxf(*op, hn);
    }
    hnxt[(size_t)brow0 * HD + j] = h_out;
  }
  {
    bool v = t < len1;
    float h_out = h1_old;
    if (v) {
      float ig = sigf(acc1.x + zx1.x + bias.x);
      float fg = sigf(acc1.y + zx1.y + bias.y);
      float gg = tanhf(acc1.z + zx1.z + bias.z);
      float og = sigf(acc1.w + zx1.w + bias.w);
      float cn = fg * c1_old + ig * gg;
      float hn = og * tanhf(cn);
      cb[(size_t)brow1 * HD + j] = cn;
      h_out = hn;
      float* op = out + (size_t)brow1 * (2 * HD) + dir * HD + j;
      *op = fmaxf(*op, hn);
    }
    hnxt[(size_t)brow1 * HD + j] = h_out;
  }
}

// ---------------- fallback (round-1 fused step) if ws too small ------------
__global__ __launch_bounds__(256) void step_fused(
    const int* __restrict__ tok, const int* __restrict__ lens,
    const float* __restrict__ emb,
    const float* __restrict__ wih_f, const float* __restrict__ whh_f,
    const float* __restrict__ bias_f,
    const float* __restrict__ wih_b, const float* __restrict__ whh_b,
    const float* __restrict__ bias_b,
    float* __restrict__ ws, float* __restrict__ out, int s) {
  const int tid = threadIdx.x;
  const int jt = blockIdx.x, bt = blockIdx.y, dir = blockIdx.z;
  const int j0 = jt * 32, b0g = bt * 16;
  const int t = (dir == 0) ? s : (TT - 1 - s);
  const float* Wih = dir ? wih_b : wih_f;
  const float* Whh = dir ? whh_b : whh_f;
  const float* bias = dir ? bias_b : bias_f;
  const float* hcur = ws + OFF_H + (size_t)((s & 1) * 2 + dir) * BB * HD;
  float* hnxt = ws + OFF_H + (size_t)(((s + 1) & 1) * 2 + dir) * BB * HD;
  float* cbuf = ws + OFF_C + (size_t)dir * BB * HD;

  __shared__ float a_sm[16][64];
  __shared__ float w_sm[64][132];
  __shared__ float z_sm[16][132];

  const int cg = tid & 31, bg = tid >> 5;
  float acc[2][4] = {{0.f, 0.f, 0.f, 0.f}, {0.f, 0.f, 0.f, 0.f}};

  for (int phase = 0; phase < 2; ++phase) {
    const float* W = phase ? Whh : Wih;
    const int K = phase ? HD : EE;
    for (int k0 = 0; k0 < K; k0 += 64) {
      const int klen = (K - k0) < 64 ? (K - k0) : 64;
      {
        int bl = tid >> 4, kk4 = tid & 15;
        if (kk4 * 4 < klen) {
          const float* src;
          if (phase == 0) {
            int tk = tok[(b0g + bl) * TT + t];
            src = emb + (size_t)tk * EE + k0 + kk4 * 4;
          } else {
            src = hcur + (size_t)(b0g + bl) * HD + k0 + kk4 * 4;
          }
          *(float4*)&a_sm[bl][kk4 * 4] = *(const float4*)src;
        }
      }
      for (int i = 0; i < 8; ++i) {
        int e = i * 256 + tid;
        int col = e >> 4, kk4 = e & 15;
        if (kk4 * 4 < klen) {
          int gcol = ((col >> 5) * HD) + j0 + (col & 31);
          float4 v = *(const float4*)(W + (size_t)gcol * K + k0 + kk4 * 4);
          w_sm[kk4 * 4 + 0][col] = v.x;
          w_sm[kk4 * 4 + 1][col] = v.y;
          w_sm[kk4 * 4 + 2][col] = v.z;
          w_sm[kk4 * 4 + 3][col] = v.w;
        }
      }
      __syncthreads();
      for (int k = 0; k < klen; ++k) {
        float a0 = a_sm[bg * 2 + 0][k];
        float a1 = a_sm[bg * 2 + 1][k];
        float4 w = *(const float4*)&w_sm[k][cg * 4];
        acc[0][0] += a0 * w.x; acc[0][1] += a0 * w.y;
        acc[0][2] += a0 * w.z; acc[0][3] += a0 * w.w;
        acc[1][0] += a1 * w.x; acc[1][1] += a1 * w.y;
        acc[1][2] += a1 * w.z; acc[1][3] += a1 * w.w;
      }
      __syncthreads();
    }
  }
  *(float4*)&z_sm[bg * 2 + 0][cg * 4] = make_float4(acc[0][0], acc[0][1], acc[0][2], acc[0][3]);
  *(float4*)&z_sm[bg * 2 + 1][cg * 4] = make_float4(acc[1][0], acc[1][1], acc[1][2], acc[1][3]);
  __syncthreads();
  for (int pi = 0; pi < 2; ++pi) {
    int p = pi * 256 + tid;
    int bl = p >> 5, jl = p & 31;
    int bglob = b0g + bl, jglob = j0 + jl;
    bool valid = t < lens[bglob];
    float h_old = hcur[(size_t)bglob * HD + jglob];
    float h_out = h_old;
    if (valid) {
      float zi = z_sm[bl][0 + jl] + bias[0 * HD + jglob];
      float zf = z_sm[bl][32 + jl] + bias[1 * HD + jglob];
      float zg = z_sm[bl][64 + jl] + bias[2 * HD + jglob];
      float zo = z_sm[bl][96 + jl] + bias[3 * HD + jglob];
      float ig = sigf(zi), fg = sigf(zf), gg = tanhf(zg), og = sigf(zo);
      float c_old = cbuf[(size_t)bglob * HD + jglob];
      float c_new = fg * c_old + ig * gg;
      float h_new = og * tanhf(c_new);
      cbuf[(size_t)bglob * HD + jglob] = c_new;
      h_out = h_new;
      float* op = out + (size_t)bglob * (2 * HD) + dir * HD + jglob;
      *op = fmaxf(*op, h_new);
    }
    hnxt[(size_t)bglob * HD + jglob] = h_out;
  }
}

extern "C" void kernel_launch(void* const* d_in, const int* in_sizes, int n_in,
                              void* d_out, int out_size, void* d_ws,
                              size_t ws_size, hipStream_t stream) {
  const int* tok = (const int*)d_in[0];
  const int* lens = (const int*)d_in[1];
  const float* emb = (const float*)d_in[2];
  const float* wih_f = (const float*)d_in[3];
  const float* whh_f = (const float*)d_in[4];
  const float* b_f = (const float*)d_in[5];
  const float* wih_b = (const float*)d_in[6];
  const float* whh_b = (const float*)d_in[7];
  const float* b_b = (const float*)d_in[8];
  float* out = (float*)d_out;
  float* ws = (float*)d_ws;

  const bool full = ws_size >= WS_FULL_BYTES;
  hipLaunchKernelGGL(init_kernel, dim3(1536), dim3(256), 0, stream, ws, out,
                     b_f, b_b, full ? 1 : 0);
  if (full) {
    hipLaunchKernelGGL(prep_whh, dim3(2048), dim3(256), 0, stream, whh_f, whh_b, ws);
    hipLaunchKernelGGL(prep_wih, dim3(2560), dim3(256), 0, stream, wih_f, wih_b, ws);
    hipLaunchKernelGGL(zx_gemm, dim3(256, 16), dim3(256), 0, stream, tok, emb, ws);
    for (int s = 0; s < TT; ++s) {
      hipLaunchKernelGGL(step_kernel, dim3(4, 32, 2), dim3(256), 0, stream,
                         lens, ws, out, s);
    }
  } else {
    for (int s = 0; s < TT; ++s) {
      hipLaunchKernelGGL(step_fused, dim3(8, 16, 2), dim3(256), 0, stream, tok,
                         lens, emb, wih_f, whh_f, b_f, wih_b, whh_b, b_b, ws,
                         out, s);
    }
  }
}

// Round 3
// 1023.952 us; speedup vs baseline: 2.5012x; 2.4098x over previous
//
#include <hip/hip_runtime.h>
#include <hip/hip_bf16.h>
#include <math.h>

#define VV 50000
#define EE 300
#define HD 256
#define BB 256
#define TT 64
#define NEGV -1e9f

// ws layout (floats):
#define OFF_H   0          // [2 buf][2 dir][B][HD]      262144
#define OFF_C   262144     // [2 dir][B][HD]             131072 (fallback only)
#define OFF_B2  393216     // [2 dir][1024] gate-interleaved bias   2048
#define OFF_WHH 395264     // [2 dir][256 k][1024 jg]    524288
#define OFF_WIH 919552     // [320 k][2 dir * 1024 jg]   655360 (rows 300..319 zero)
#define OFF_ZX  1574912    // [(b*64+t)][2048]           33554432
#define OFF_CTR 35129344   // [64] u32 barrier counters
#define WS_FULL_BYTES ((35129344ULL + 64ULL) * 4ULL)

__device__ __forceinline__ float sigf(float x) {
  return 1.f / (1.f + __expf(-x));
}
__device__ __forceinline__ float tanhfast(float x) {
  return 1.f - 2.f / (__expf(2.f * x) + 1.f);
}

// ---------------- init: zero H/C, out=-1e9, bias interleave, ctr=0 ---------
__global__ __launch_bounds__(256) void init_kernel(float* __restrict__ ws,
                                                   float* __restrict__ out,
                                                   const float* __restrict__ bf,
                                                   const float* __restrict__ bb,
                                                   int full) {
  int idx = blockIdx.x * 256 + threadIdx.x;
  if (idx < 393216) ws[idx] = 0.f;
  if (idx < BB * 2 * HD) out[idx] = NEGV;
  if (full && idx < 2048) {
    int dir = idx >> 10, jg = idx & 1023, j = jg >> 2, g = jg & 3;
    ws[OFF_B2 + idx] = (dir ? bb : bf)[g * HD + j];
  }
  if (full && idx < 64) ((unsigned int*)(ws + OFF_CTR))[idx] = 0u;
}

// ---------------- prep: transpose W_hh -> [dir][k][j*4+g] ------------------
__global__ __launch_bounds__(256) void prep_whh(const float* __restrict__ wf,
                                                const float* __restrict__ wb,
                                                float* __restrict__ ws) {
  int o = blockIdx.x * 256 + threadIdx.x;  // < 524288
  int dir = o >> 18, r = o & 262143, k = r >> 10, jg = r & 1023;
  int j = jg >> 2, g = jg & 3;
  const float* W = dir ? wb : wf;
  ws[OFF_WHH + o] = W[(size_t)((g << 8) + j) * HD + k];
}

// ---------------- prep: transpose W_ih -> [k(320)][dir*1024 + j*4+g] -------
__global__ __launch_bounds__(256) void prep_wih(const float* __restrict__ wf,
                                                const float* __restrict__ wb,
                                                float* __restrict__ ws) {
  int o = blockIdx.x * 256 + threadIdx.x;  // < 655360
  int k = o >> 11, r = o & 2047, dir = r >> 10, jg = r & 1023;
  int j = jg >> 2, g = jg & 3;
  float v = 0.f;
  if (k < EE) {
    const float* W = dir ? wb : wf;
    v = W[(size_t)((g << 8) + j) * EE + k];
  }
  ws[OFF_WIH + o] = v;
}

// ---------------- Zx = X @ Wih^T for all (b,t): M=16384 N=2048 K=300 -------
__global__ __launch_bounds__(256) void zx_gemm(const int* __restrict__ tok,
                                               const float* __restrict__ emb,
                                               float* __restrict__ ws) {
  __shared__ float a_sm[64][68];
  __shared__ float b_sm[64][132];
  const int tid = threadIdx.x;
  const int m0 = blockIdx.x * 64;
  const int n0 = blockIdx.y * 128;
  const float* wih = ws + OFF_WIH;
  float* zx = ws + OFF_ZX;

  float acc[4][8];
#pragma unroll
  for (int i = 0; i < 4; ++i)
#pragma unroll
    for (int jj = 0; jj < 8; ++jj) acc[i][jj] = 0.f;

  const int arow = tid >> 2, aq = tid & 3;
  const int tokv = tok[m0 + arow];
  const float* er = emb + (size_t)tokv * EE;
  const int mg = (tid >> 4) * 4;
  const int ng = (tid & 15) * 8;

  for (int kc = 0; kc < 5; ++kc) {
    const int k0 = kc * 64;
#pragma unroll
    for (int i = 0; i < 4; ++i) {
      int c = aq * 16 + i * 4;
      float4 v = make_float4(0.f, 0.f, 0.f, 0.f);
      if (k0 + c + 3 < EE) v = *(const float4*)(er + k0 + c);
      *(float4*)&a_sm[arow][c] = v;
    }
    const float* bs = wih + (size_t)(k0 + arow) * 2048 + n0;
#pragma unroll
    for (int i = 0; i < 8; ++i) {
      int n = aq * 32 + i * 4;
      *(float4*)&b_sm[arow][n] = *(const float4*)(bs + n);
    }
    __syncthreads();
#pragma unroll 8
    for (int k = 0; k < 64; ++k) {
      float a[4];
#pragma unroll
      for (int i = 0; i < 4; ++i) a[i] = a_sm[mg + i][k];
      float4 b0 = *(const float4*)&b_sm[k][ng];
      float4 b1 = *(const float4*)&b_sm[k][ng + 4];
#pragma unroll
      for (int i = 0; i < 4; ++i) {
        acc[i][0] += a[i] * b0.x; acc[i][1] += a[i] * b0.y;
        acc[i][2] += a[i] * b0.z; acc[i][3] += a[i] * b0.w;
        acc[i][4] += a[i] * b1.x; acc[i][5] += a[i] * b1.y;
        acc[i][6] += a[i] * b1.z; acc[i][7] += a[i] * b1.w;
      }
    }
    __syncthreads();
  }
#pragma unroll
  for (int i = 0; i < 4; ++i) {
    float* dst = zx + (size_t)(m0 + mg + i) * 2048 + n0 + ng;
    *(float4*)dst = make_float4(acc[i][0], acc[i][1], acc[i][2], acc[i][3]);
    *(float4*)(dst + 4) = make_float4(acc[i][4], acc[i][5], acc[i][6], acc[i][7]);
  }
}

// ---------------- persistent recurrence: W register-stationary -------------
// grid = (32 bgroup, 4 slice, 2 dir) x 512 threads, 1 block/CU.
// thread: wv = tid>>6 (kseg in FMA stage; batch row in gate stage),
//         ln = tid&63 (jg-quad within slice).
__global__ __launch_bounds__(512, 2) void lstm_persist(
    const int* __restrict__ lens, float* __restrict__ ws,
    float* __restrict__ out) {
  const int g = blockIdx.x;      // 0..31
  const int slice = blockIdx.y;  // 0..3
  const int dir = blockIdx.z;    // 0..1
  const int tid = threadIdx.x;
  const int wv = tid >> 6;
  const int ln = tid & 63;

  __shared__ float h_sm[8][256];
  __shared__ float red_sm[8][2048];

  // W slice into registers: w[k] = Whh_t[dir][wv*32+k][slice*256 + ln*4 ..+3]
  float4 w[32];
  {
    const float* wp = ws + OFF_WHH + (size_t)dir * 262144 +
                      (size_t)(wv * 32) * 1024 + slice * 256 + ln * 4;
#pragma unroll
    for (int k = 0; k < 32; ++k) w[k] = *(const float4*)(wp + (size_t)k * 1024);
  }
  const int brow = g * 8 + wv;
  const int len = lens[brow];
  const float4 bias =
      *(const float4*)(ws + OFF_B2 + dir * 1024 + slice * 256 + ln * 4);
  float c = 0.f, omax = NEGV;
  unsigned int* ctr = (unsigned int*)(ws + OFF_CTR) + dir * 32 + g;
  const float* zx = ws + OFF_ZX;
  float* hb = ws + OFF_H;  // [2 buf][2 dir][256 b][256 j]
  const int j = slice * 64 + ln;

  for (int s = 0; s < TT; ++s) {
    const int t = dir ? (TT - 1 - s) : s;
    // stage h(s) from buf s&1
    {
      const float* src =
          hb + (size_t)((((s & 1) * 2 + dir) * 256) + g * 8 + wv) * 256 + ln * 4;
      *(float4*)&h_sm[wv][ln * 4] = *(const float4*)src;
    }
    __syncthreads();
    // FMA over k window [wv*32, wv*32+32)
    float4 acc[8];
#pragma unroll
    for (int r = 0; r < 8; ++r) acc[r] = make_float4(0.f, 0.f, 0.f, 0.f);
#pragma unroll
    for (int kq = 0; kq < 8; ++kq) {
      float4 h4[8];
#pragma unroll
      for (int r = 0; r < 8; ++r)
        h4[r] = *(const float4*)&h_sm[r][wv * 32 + kq * 4];
#pragma unroll
      for (int kk = 0; kk < 4; ++kk) {
#pragma unroll
        for (int r = 0; r < 8; ++r) {
          float hv = kk == 0 ? h4[r].x : kk == 1 ? h4[r].y
                     : kk == 2 ? h4[r].z : h4[r].w;
          float4 wk = w[kq * 4 + kk];
          acc[r].x += hv * wk.x; acc[r].y += hv * wk.y;
          acc[r].z += hv * wk.z; acc[r].w += hv * wk.w;
        }
      }
    }
#pragma unroll
    for (int r = 0; r < 8; ++r)
      *(float4*)&red_sm[wv][r * 256 + ln * 4] = acc[r];
    __syncthreads();
    // reduce 8 ksegs for (row=wv, quad=ln)
    float4 z = make_float4(0.f, 0.f, 0.f, 0.f);
#pragma unroll
    for (int ks = 0; ks < 8; ++ks) {
      float4 p = *(const float4*)&red_sm[ks][wv * 256 + ln * 4];
      z.x += p.x; z.y += p.y; z.z += p.z; z.w += p.w;
    }
    const float4 zx4 = *(const float4*)(zx + ((size_t)brow * TT + t) * 2048 +
                                        dir * 1024 + slice * 256 + ln * 4);
    float h_old = h_sm[wv][j];
    float h_out = h_old;
    if (t < len) {
      float ig = sigf(z.x + zx4.x + bias.x);
      float fg = sigf(z.y + zx4.y + bias.y);
      float gg = tanhfast(z.z + zx4.z + bias.z);
      float og = sigf(z.w + zx4.w + bias.w);
      c = fg * c + ig * gg;
      float hn = og * tanhfast(c);
      h_out = hn;
      omax = fmaxf(omax, hn);
    }
    hb[(size_t)(((((s + 1) & 1) * 2 + dir) * 256) + brow) * 256 + j] = h_out;
    __syncthreads();  // all lanes finished h_sm reads + h writes issued
    if (tid == 0) {
      __hip_atomic_fetch_add(ctr, 1u, __ATOMIC_RELEASE,
                             __HIP_MEMORY_SCOPE_AGENT);
      unsigned int target = 4u * (unsigned)(s + 1);
      while (__hip_atomic_load(ctr, __ATOMIC_ACQUIRE,
                               __HIP_MEMORY_SCOPE_AGENT) < target) {
      }
    }
    __syncthreads();
  }
  out[(size_t)brow * (2 * HD) + dir * HD + j] = omax;
}

// ---------------- fallback (round-1 fused step) if ws too small ------------
__global__ __launch_bounds__(256) void step_fused(
    const int* __restrict__ tok, const int* __restrict__ lens,
    const float* __restrict__ emb,
    const float* __restrict__ wih_f, const float* __restrict__ whh_f,
    const float* __restrict__ bias_f,
    const float* __restrict__ wih_b, const float* __restrict__ whh_b,
    const float* __restrict__ bias_b,
    float* __restrict__ ws, float* __restrict__ out, int s) {
  const int tid = threadIdx.x;
  const int jt = blockIdx.x, bt = blockIdx.y, dir = blockIdx.z;
  const int j0 = jt * 32, b0g = bt * 16;
  const int t = (dir == 0) ? s : (TT - 1 - s);
  const float* Wih = dir ? wih_b : wih_f;
  const float* Whh = dir ? whh_b : whh_f;
  const float* bias = dir ? bias_b : bias_f;
  const float* hcur = ws + OFF_H + (size_t)((s & 1) * 2 + dir) * BB * HD;
  float* hnxt = ws + OFF_H + (size_t)(((s + 1) & 1) * 2 + dir) * BB * HD;
  float* cbuf = ws + OFF_C + (size_t)dir * BB * HD;

  __shared__ float a_sm[16][64];
  __shared__ float w_sm[64][132];
  __shared__ float z_sm[16][132];

  const int cg = tid & 31, bg = tid >> 5;
  float acc[2][4] = {{0.f, 0.f, 0.f, 0.f}, {0.f, 0.f, 0.f, 0.f}};

  for (int phase = 0; phase < 2; ++phase) {
    const float* W = phase ? Whh : Wih;
    const int K = phase ? HD : EE;
    for (int k0 = 0; k0 < K; k0 += 64) {
      const int klen = (K - k0) < 64 ? (K - k0) : 64;
      {
        int bl = tid >> 4, kk4 = tid & 15;
        if (kk4 * 4 < klen) {
          const float* src;
          if (phase == 0) {
            int tk = tok[(b0g + bl) * TT + t];
            src = emb + (size_t)tk * EE + k0 + kk4 * 4;
          } else {
            src = hcur + (size_t)(b0g + bl) * HD + k0 + kk4 * 4;
          }
          *(float4*)&a_sm[bl][kk4 * 4] = *(const float4*)src;
        }
      }
      for (int i = 0; i < 8; ++i) {
        int e = i * 256 + tid;
        int col = e >> 4, kk4 = e & 15;
        if (kk4 * 4 < klen) {
          int gcol = ((col >> 5) * HD) + j0 + (col & 31);
          float4 v = *(const float4*)(W + (size_t)gcol * K + k0 + kk4 * 4);
          w_sm[kk4 * 4 + 0][col] = v.x;
          w_sm[kk4 * 4 + 1][col] = v.y;
          w_sm[kk4 * 4 + 2][col] = v.z;
          w_sm[kk4 * 4 + 3][col] = v.w;
        }
      }
      __syncthreads();
      for (int k = 0; k < klen; ++k) {
        float a0 = a_sm[bg * 2 + 0][k];
        float a1 = a_sm[bg * 2 + 1][k];
        float4 w = *(const float4*)&w_sm[k][cg * 4];
        acc[0][0] += a0 * w.x; acc[0][1] += a0 * w.y;
        acc[0][2] += a0 * w.z; acc[0][3] += a0 * w.w;
        acc[1][0] += a1 * w.x; acc[1][1] += a1 * w.y;
        acc[1][2] += a1 * w.z; acc[1][3] += a1 * w.w;
      }
      __syncthreads();
    }
  }
  *(float4*)&z_sm[bg * 2 + 0][cg * 4] =
      make_float4(acc[0][0], acc[0][1], acc[0][2], acc[0][3]);
  *(float4*)&z_sm[bg * 2 + 1][cg * 4] =
      make_float4(acc[1][0], acc[1][1], acc[1][2], acc[1][3]);
  __syncthreads();
  for (int pi = 0; pi < 2; ++pi) {
    int p = pi * 256 + tid;
    int bl = p >> 5, jl = p & 31;
    int bglob = b0g + bl, jglob = j0 + jl;
    bool valid = t < lens[bglob];
    float h_old = hcur[(size_t)bglob * HD + jglob];
    float h_out = h_old;
    if (valid) {
      float zi = z_sm[bl][0 + jl] + bias[0 * HD + jglob];
      float zf = z_sm[bl][32 + jl] + bias[1 * HD + jglob];
      float zg = z_sm[bl][64 + jl] + bias[2 * HD + jglob];
      float zo = z_sm[bl][96 + jl] + bias[3 * HD + jglob];
      float ig = sigf(zi), fg = sigf(zf), gg = tanhf(zg), og = sigf(zo);
      float c_old = cbuf[(size_t)bglob * HD + jglob];
      float c_new = fg * c_old + ig * gg;
      float h_new = og * tanhf(c_new);
      cbuf[(size_t)bglob * HD + jglob] = c_new;
      h_out = h_new;
      float* op = out + (size_t)bglob * (2 * HD) + dir * HD + jglob;
      *op = fmaxf(*op, h_new);
    }
    hnxt[(size_t)bglob * HD + jglob] = h_out;
  }
}

extern "C" void kernel_launch(void* const* d_in, const int* in_sizes, int n_in,
                              void* d_out, int out_size, void* d_ws,
                              size_t ws_size, hipStream_t stream) {
  const int* tok = (const int*)d_in[0];
  const int* lens = (const int*)d_in[1];
  const float* emb = (const float*)d_in[2];
  const float* wih_f = (const float*)d_in[3];
  const float* whh_f = (const float*)d_in[4];
  const float* b_f = (const float*)d_in[5];
  const float* wih_b = (const float*)d_in[6];
  const float* whh_b = (const float*)d_in[7];
  const float* b_b = (const float*)d_in[8];
  float* out = (float*)d_out;
  float* ws = (float*)d_ws;

  const bool full = ws_size >= WS_FULL_BYTES;
  hipLaunchKernelGGL(init_kernel, dim3(1536), dim3(256), 0, stream, ws, out,
                     b_f, b_b, full ? 1 : 0);
  if (full) {
    hipLaunchKernelGGL(prep_whh, dim3(2048), dim3(256), 0, stream, whh_f,
                       whh_b, ws);
    hipLaunchKernelGGL(prep_wih, dim3(2560), dim3(256), 0, stream, wih_f,
                       wih_b, ws);
    hipLaunchKernelGGL(zx_gemm, dim3(256, 16), dim3(256), 0, stream, tok, emb,
                       ws);
    hipLaunchKernelGGL(lstm_persist, dim3(32, 4, 2), dim3(512), 0, stream,
                       lens, ws, out);
  } else {
    for (int s = 0; s < TT; ++s) {
      hipLaunchKernelGGL(step_fused, dim3(8, 16, 2), dim3(256), 0, stream, tok,
                         lens, emb, wih_f, whh_f, b_f, wih_b, whh_b, b_b, ws,
                         out, s);
    }
  }
}

// Round 4
// 659.822 us; speedup vs baseline: 3.8815x; 1.5519x over previous
//
#include <hip/hip_runtime.h>
#include <hip/hip_bf16.h>
#include <math.h>

#define VV 50000
#define EE 300
#define HD 256
#define BB 256
#define TT 64
#define NEGV -1e9f

// ws layout (floats):
#define OFF_H   0          // [2 buf][2 dir][B][HD]      262144
#define OFF_C   262144     // [2 dir][B][HD]             131072 (fallback only)
#define OFF_B2  393216     // [2 dir][1024] gate-interleaved bias   2048
#define OFF_WHH 395264     // [2 dir][256 k][1024 jg]    524288
#define OFF_WIH 919552     // [320 k][2 dir * 1024 jg]   655360 (rows 300..319 zero)
#define OFF_ZX  1574912    // [(b*64+t)][2048]           33554432
#define OFF_CTR 35129344   // [64] u32 barrier counters
#define WS_FULL_BYTES ((35129344ULL + 64ULL) * 4ULL)

__device__ __forceinline__ float sigf(float x) {
  return 1.f / (1.f + __expf(-x));
}
__device__ __forceinline__ float tanhfast(float x) {
  return 1.f - 2.f / (__expf(2.f * x) + 1.f);
}

// ---------------- init: zero H/C, out=-1e9, bias interleave, ctr=0 ---------
__global__ __launch_bounds__(256) void init_kernel(float* __restrict__ ws,
                                                   float* __restrict__ out,
                                                   const float* __restrict__ bf,
                                                   const float* __restrict__ bb,
                                                   int full) {
  int idx = blockIdx.x * 256 + threadIdx.x;
  if (idx < 393216) ws[idx] = 0.f;
  if (idx < BB * 2 * HD) out[idx] = NEGV;
  if (full && idx < 2048) {
    int dir = idx >> 10, jg = idx & 1023, j = jg >> 2, g = jg & 3;
    ws[OFF_B2 + idx] = (dir ? bb : bf)[g * HD + j];
  }
  if (full && idx < 64) ((unsigned int*)(ws + OFF_CTR))[idx] = 0u;
}

// ---------------- prep: transpose W_hh -> [dir][k][j*4+g] ------------------
__global__ __launch_bounds__(256) void prep_whh(const float* __restrict__ wf,
                                                const float* __restrict__ wb,
                                                float* __restrict__ ws) {
  int o = blockIdx.x * 256 + threadIdx.x;  // < 524288
  int dir = o >> 18, r = o & 262143, k = r >> 10, jg = r & 1023;
  int j = jg >> 2, g = jg & 3;
  const float* W = dir ? wb : wf;
  ws[OFF_WHH + o] = W[(size_t)((g << 8) + j) * HD + k];
}

// ---------------- prep: transpose W_ih -> [k(320)][dir*1024 + j*4+g] -------
__global__ __launch_bounds__(256) void prep_wih(const float* __restrict__ wf,
                                                const float* __restrict__ wb,
                                                float* __restrict__ ws) {
  int o = blockIdx.x * 256 + threadIdx.x;  // < 655360
  int k = o >> 11, r = o & 2047, dir = r >> 10, jg = r & 1023;
  int j = jg >> 2, g = jg & 3;
  float v = 0.f;
  if (k < EE) {
    const float* W = dir ? wb : wf;
    v = W[(size_t)((g << 8) + j) * EE + k];
  }
  ws[OFF_WIH + o] = v;
}

// ---------------- Zx = X @ Wih^T for all (b,t): M=16384 N=2048 K=300 -------
__global__ __launch_bounds__(256) void zx_gemm(const int* __restrict__ tok,
                                               const float* __restrict__ emb,
                                               float* __restrict__ ws) {
  __shared__ float a_sm[64][68];
  __shared__ float b_sm[64][132];
  const int tid = threadIdx.x;
  const int m0 = blockIdx.x * 64;
  const int n0 = blockIdx.y * 128;
  const float* wih = ws + OFF_WIH;
  float* zx = ws + OFF_ZX;

  float acc[4][8];
#pragma unroll
  for (int i = 0; i < 4; ++i)
#pragma unroll
    for (int jj = 0; jj < 8; ++jj) acc[i][jj] = 0.f;

  const int arow = tid >> 2, aq = tid & 3;
  const int tokv = tok[m0 + arow];
  const float* er = emb + (size_t)tokv * EE;
  const int mg = (tid >> 4) * 4;  // 4 m rows per thread
  const int ng = (tid & 15) * 4;  // cols [ng..ng+3] and [64+ng..64+ng+3]

  for (int kc = 0; kc < 5; ++kc) {
    const int k0 = kc * 64;
#pragma unroll
    for (int i = 0; i < 4; ++i) {
      int c = aq * 16 + i * 4;
      float4 v = make_float4(0.f, 0.f, 0.f, 0.f);
      if (k0 + c + 3 < EE) v = *(const float4*)(er + k0 + c);
      *(float4*)&a_sm[arow][c] = v;
    }
    const float* bs = wih + (size_t)(k0 + arow) * 2048 + n0;
#pragma unroll
    for (int i = 0; i < 8; ++i) {
      int n = aq * 32 + i * 4;
      *(float4*)&b_sm[arow][n] = *(const float4*)(bs + n);
    }
    __syncthreads();
#pragma unroll
    for (int kq = 0; kq < 16; ++kq) {
      float4 a4[4];
#pragma unroll
      for (int i = 0; i < 4; ++i) a4[i] = *(const float4*)&a_sm[mg + i][kq * 4];
#pragma unroll
      for (int kk = 0; kk < 4; ++kk) {
        float4 b0 = *(const float4*)&b_sm[kq * 4 + kk][ng];
        float4 b1 = *(const float4*)&b_sm[kq * 4 + kk][64 + ng];
#pragma unroll
        for (int i = 0; i < 4; ++i) {
          float av = kk == 0 ? a4[i].x : kk == 1 ? a4[i].y
                     : kk == 2 ? a4[i].z : a4[i].w;
          acc[i][0] += av * b0.x; acc[i][1] += av * b0.y;
          acc[i][2] += av * b0.z; acc[i][3] += av * b0.w;
          acc[i][4] += av * b1.x; acc[i][5] += av * b1.y;
          acc[i][6] += av * b1.z; acc[i][7] += av * b1.w;
        }
      }
    }
    __syncthreads();
  }
#pragma unroll
  for (int i = 0; i < 4; ++i) {
    float* dst = zx + (size_t)(m0 + mg + i) * 2048 + n0;
    *(float4*)(dst + ng) = make_float4(acc[i][0], acc[i][1], acc[i][2], acc[i][3]);
    *(float4*)(dst + 64 + ng) =
        make_float4(acc[i][4], acc[i][5], acc[i][6], acc[i][7]);
  }
}

// ---------------- persistent recurrence: W register-stationary -------------
// grid = (32 bgroup, 4 slice, 2 dir) x 512 threads, 1 block/CU.
// Cross-block h exchange via RELAXED agent-scope point atomics (sc1), no
// bulk wbl2/inv; ordering = per-wave vmcnt(0) drain before relaxed flag add.
__global__ __launch_bounds__(512, 2) void lstm_persist(
    const int* __restrict__ lens, float* __restrict__ ws,
    float* __restrict__ out) {
  const int g = blockIdx.x;      // 0..31
  const int slice = blockIdx.y;  // 0..3
  const int dir = blockIdx.z;    // 0..1
  const int tid = threadIdx.x;
  const int wv = tid >> 6;
  const int ln = tid & 63;

  __shared__ float h_sm[8][256];
  __shared__ float red_sm[8][2048];

  // W slice into registers: w[k] = Whh_t[dir][wv*32+k][slice*256 + ln*4 ..+3]
  float4 w[32];
  {
    const float* wp = ws + OFF_WHH + (size_t)dir * 262144 +
                      (size_t)(wv * 32) * 1024 + slice * 256 + ln * 4;
#pragma unroll
    for (int k = 0; k < 32; ++k) w[k] = *(const float4*)(wp + (size_t)k * 1024);
  }
  const int brow = g * 8 + wv;
  const int len = lens[brow];
  const float4 bias =
      *(const float4*)(ws + OFF_B2 + dir * 1024 + slice * 256 + ln * 4);
  float c = 0.f, omax = NEGV;
  unsigned int* ctr = (unsigned int*)(ws + OFF_CTR) + dir * 32 + g;
  const float* zx = ws + OFF_ZX;
  float* hb = ws + OFF_H;  // [2 buf][2 dir][256 b][256 j]
  const int j = slice * 64 + ln;

  for (int s = 0; s < TT; ++s) {
    const int t = dir ? (TT - 1 - s) : s;
    // independent-of-h loads first (hide under FMA)
    const float4 zx4 = *(const float4*)(zx + ((size_t)brow * TT + t) * 2048 +
                                        dir * 1024 + slice * 256 + ln * 4);
    // stage h(s) from buf s&1 via coherent point loads (2x u64 per thread)
    {
      const float* src =
          hb + (size_t)((((s & 1) * 2 + dir) * 256) + g * 8 + wv) * 256 + ln * 4;
      const unsigned long long* s8 = (const unsigned long long*)src;
      unsigned long long u0 =
          __hip_atomic_load(s8 + 0, __ATOMIC_RELAXED, __HIP_MEMORY_SCOPE_AGENT);
      unsigned long long u1 =
          __hip_atomic_load(s8 + 1, __ATOMIC_RELAXED, __HIP_MEMORY_SCOPE_AGENT);
      float2 f0, f1;
      __builtin_memcpy(&f0, &u0, 8);
      __builtin_memcpy(&f1, &u1, 8);
      h_sm[wv][ln * 4 + 0] = f0.x;
      h_sm[wv][ln * 4 + 1] = f0.y;
      h_sm[wv][ln * 4 + 2] = f1.x;
      h_sm[wv][ln * 4 + 3] = f1.y;
    }
    __syncthreads();
    // FMA over k window [wv*32, wv*32+32)
    float4 acc[8];
#pragma unroll
    for (int r = 0; r < 8; ++r) acc[r] = make_float4(0.f, 0.f, 0.f, 0.f);
#pragma unroll
    for (int kq = 0; kq < 8; ++kq) {
      float4 h4[8];
#pragma unroll
      for (int r = 0; r < 8; ++r)
        h4[r] = *(const float4*)&h_sm[r][wv * 32 + kq * 4];
#pragma unroll
      for (int kk = 0; kk < 4; ++kk) {
#pragma unroll
        for (int r = 0; r < 8; ++r) {
          float hv = kk == 0 ? h4[r].x : kk == 1 ? h4[r].y
                     : kk == 2 ? h4[r].z : h4[r].w;
          float4 wk = w[kq * 4 + kk];
          acc[r].x += hv * wk.x; acc[r].y += hv * wk.y;
          acc[r].z += hv * wk.z; acc[r].w += hv * wk.w;
        }
      }
    }
#pragma unroll
    for (int r = 0; r < 8; ++r)
      *(float4*)&red_sm[wv][r * 256 + ln * 4] = acc[r];
    __syncthreads();
    // reduce 8 ksegs for (row=wv, quad=ln)
    float4 z = make_float4(0.f, 0.f, 0.f, 0.f);
#pragma unroll
    for (int ks = 0; ks < 8; ++ks) {
      float4 p = *(const float4*)&red_sm[ks][wv * 256 + ln * 4];
      z.x += p.x; z.y += p.y; z.z += p.z; z.w += p.w;
    }
    float h_old = h_sm[wv][j];
    float h_out = h_old;
    if (t < len) {
      float ig = sigf(z.x + zx4.x + bias.x);
      float fg = sigf(z.y + zx4.y + bias.y);
      float gg = tanhfast(z.z + zx4.z + bias.z);
      float og = sigf(z.w + zx4.w + bias.w);
      c = fg * c + ig * gg;
      float hn = og * tanhfast(c);
      h_out = hn;
      omax = fmaxf(omax, hn);
    }
    if (s < TT - 1) {
      float* dst =
          hb + (size_t)(((((s + 1) & 1) * 2 + dir) * 256) + brow) * 256 + j;
      __hip_atomic_store(dst, h_out, __ATOMIC_RELAXED,
                         __HIP_MEMORY_SCOPE_AGENT);
      asm volatile("s_waitcnt vmcnt(0)" ::: "memory");
      __syncthreads();  // all waves drained their h stores
      if (tid == 0) {
        __hip_atomic_fetch_add(ctr, 1u, __ATOMIC_RELAXED,
                               __HIP_MEMORY_SCOPE_AGENT);
        const unsigned int target = 4u * (unsigned)(s + 1);
        while (__hip_atomic_load(ctr, __ATOMIC_RELAXED,
                                 __HIP_MEMORY_SCOPE_AGENT) < target) {
        }
      }
      __syncthreads();
    }
  }
  out[(size_t)brow * (2 * HD) + dir * HD + j] = omax;
}

// ---------------- fallback (round-1 fused step) if ws too small ------------
__global__ __launch_bounds__(256) void step_fused(
    const int* __restrict__ tok, const int* __restrict__ lens,
    const float* __restrict__ emb,
    const float* __restrict__ wih_f, const float* __restrict__ whh_f,
    const float* __restrict__ bias_f,
    const float* __restrict__ wih_b, const float* __restrict__ whh_b,
    const float* __restrict__ bias_b,
    float* __restrict__ ws, float* __restrict__ out, int s) {
  const int tid = threadIdx.x;
  const int jt = blockIdx.x, bt = blockIdx.y, dir = blockIdx.z;
  const int j0 = jt * 32, b0g = bt * 16;
  const int t = (dir == 0) ? s : (TT - 1 - s);
  const float* Wih = dir ? wih_b : wih_f;
  const float* Whh = dir ? whh_b : whh_f;
  const float* bias = dir ? bias_b : bias_f;
  const float* hcur = ws + OFF_H + (size_t)((s & 1) * 2 + dir) * BB * HD;
  float* hnxt = ws + OFF_H + (size_t)(((s + 1) & 1) * 2 + dir) * BB * HD;
  float* cbuf = ws + OFF_C + (size_t)dir * BB * HD;

  __shared__ float a_sm[16][64];
  __shared__ float w_sm[64][132];
  __shared__ float z_sm[16][132];

  const int cg = tid & 31, bg = tid >> 5;
  float acc[2][4] = {{0.f, 0.f, 0.f, 0.f}, {0.f, 0.f, 0.f, 0.f}};

  for (int phase = 0; phase < 2; ++phase) {
    const float* W = phase ? Whh : Wih;
    const int K = phase ? HD : EE;
    for (int k0 = 0; k0 < K; k0 += 64) {
      const int klen = (K - k0) < 64 ? (K - k0) : 64;
      {
        int bl = tid >> 4, kk4 = tid & 15;
        if (kk4 * 4 < klen) {
          const float* src;
          if (phase == 0) {
            int tk = tok[(b0g + bl) * TT + t];
            src = emb + (size_t)tk * EE + k0 + kk4 * 4;
          } else {
            src = hcur + (size_t)(b0g + bl) * HD + k0 + kk4 * 4;
          }
          *(float4*)&a_sm[bl][kk4 * 4] = *(const float4*)src;
        }
      }
      for (int i = 0; i < 8; ++i) {
        int e = i * 256 + tid;
        int col = e >> 4, kk4 = e & 15;
        if (kk4 * 4 < klen) {
          int gcol = ((col >> 5) * HD) + j0 + (col & 31);
          float4 v = *(const float4*)(W + (size_t)gcol * K + k0 + kk4 * 4);
          w_sm[kk4 * 4 + 0][col] = v.x;
          w_sm[kk4 * 4 + 1][col] = v.y;
          w_sm[kk4 * 4 + 2][col] = v.z;
          w_sm[kk4 * 4 + 3][col] = v.w;
        }
      }
      __syncthreads();
      for (int k = 0; k < klen; ++k) {
        float a0 = a_sm[bg * 2 + 0][k];
        float a1 = a_sm[bg * 2 + 1][k];
        float4 w = *(const float4*)&w_sm[k][cg * 4];
        acc[0][0] += a0 * w.x; acc[0][1] += a0 * w.y;
        acc[0][2] += a0 * w.z; acc[0][3] += a0 * w.w;
        acc[1][0] += a1 * w.x; acc[1][1] += a1 * w.y;
        acc[1][2] += a1 * w.z; acc[1][3] += a1 * w.w;
      }
      __syncthreads();
    }
  }
  *(float4*)&z_sm[bg * 2 + 0][cg * 4] =
      make_float4(acc[0][0], acc[0][1], acc[0][2], acc[0][3]);
  *(float4*)&z_sm[bg * 2 + 1][cg * 4] =
      make_float4(acc[1][0], acc[1][1], acc[1][2], acc[1][3]);
  __syncthreads();
  for (int pi = 0; pi < 2; ++pi) {
    int p = pi * 256 + tid;
    int bl = p >> 5, jl = p & 31;
    int bglob = b0g + bl, jglob = j0 + jl;
    bool valid = t < lens[bglob];
    float h_old = hcur[(size_t)bglob * HD + jglob];
    float h_out = h_old;
    if (valid) {
      float zi = z_sm[bl][0 + jl] + bias[0 * HD + jglob];
      float zf = z_sm[bl][32 + jl] + bias[1 * HD + jglob];
      float zg = z_sm[bl][64 + jl] + bias[2 * HD + jglob];
      float zo = z_sm[bl][96 + jl] + bias[3 * HD + jglob];
      float ig = sigf(zi), fg = sigf(zf), gg = tanhf(zg), og = sigf(zo);
      float c_old = cbuf[(size_t)bglob * HD + jglob];
      float c_new = fg * c_old + ig * gg;
      float h_new = og * tanhf(c_new);
      cbuf[(size_t)bglob * HD + jglob] = c_new;
      h_out = h_new;
      float* op = out + (size_t)bglob * (2 * HD) + dir * HD + jglob;
      *op = fmaxf(*op, h_new);
    }
    hnxt[(size_t)bglob * HD + jglob] = h_out;
  }
}

extern "C" void kernel_launch(void* const* d_in, const int* in_sizes, int n_in,
                              void* d_out, int out_size, void* d_ws,
                              size_t ws_size, hipStream_t stream) {
  const int* tok = (const int*)d_in[0];
  const int* lens = (const int*)d_in[1];
  const float* emb = (const float*)d_in[2];
  const float* wih_f = (const float*)d_in[3];
  const float* whh_f = (const float*)d_in[4];
  const float* b_f = (const float*)d_in[5];
  const float* wih_b = (const float*)d_in[6];
  const float* whh_b = (const float*)d_in[7];
  const float* b_b = (const float*)d_in[8];
  float* out = (float*)d_out;
  float* ws = (float*)d_ws;

  const bool full = ws_size >= WS_FULL_BYTES;
  hipLaunchKernelGGL(init_kernel, dim3(1536), dim3(256), 0, stream, ws, out,
                     b_f, b_b, full ? 1 : 0);
  if (full) {
    hipLaunchKernelGGL(prep_whh, dim3(2048), dim3(256), 0, stream, whh_f,
                       whh_b, ws);
    hipLaunchKernelGGL(prep_wih, dim3(2560), dim3(256), 0, stream, wih_f,
                       wih_b, ws);
    hipLaunchKernelGGL(zx_gemm, dim3(256, 16), dim3(256), 0, stream, tok, emb,
                       ws);
    hipLaunchKernelGGL(lstm_persist, dim3(32, 4, 2), dim3(512), 0, stream,
                       lens, ws, out);
  } else {
    for (int s = 0; s < TT; ++s) {
      hipLaunchKernelGGL(step_fused, dim3(8, 16, 2), dim3(256), 0, stream, tok,
                         lens, emb, wih_f, whh_f, b_f, wih_b, whh_b, b_b, ws,
                         out, s);
    }
  }
}

// Round 5
// 410.540 us; speedup vs baseline: 6.2383x; 1.6072x over previous
//
#include <hip/hip_runtime.h>
#include <hip/hip_bf16.h>
#include <math.h>

#define VV 50000
#define EE 300
#define HD 256
#define BB 256
#define TT 64
#define NEGV -1e9f

// ws layout (floats):
#define OFF_H    0         // [2 buf][2 dir][B][HD]      262144
#define OFF_C    262144    // fallback C-state; full path: padded barrier ctrs
#define OFF_CTR  262144    // [64 chains][32 u32] (128 B stride)  2048 u32
#define OFF_B2   393216    // [2 dir][1024] gate-interleaved bias   2048
#define OFF_WHH  395264    // [dir][256 k][1024 jg] fp32          524288
#define OFF_WIHB 919552    // bf16 [2048 n][320 k] = 327680 floats
#define OFF_ZX   1574912   // [(b*64+t)][2048] fp32               33554432
#define WS_FULL_BYTES ((35129344ULL + 64ULL) * 4ULL)

typedef __attribute__((ext_vector_type(8))) short bf16x8;
typedef __attribute__((ext_vector_type(16))) float f32x16;

__device__ __forceinline__ float sigf(float x) {
  return 1.f / (1.f + __expf(-x));
}
__device__ __forceinline__ float tanhfast(float x) {
  return 1.f - 2.f / (__expf(2.f * x) + 1.f);
}
__device__ __forceinline__ unsigned short f2bf(float f) {
  union { float f; unsigned u; } x;
  x.f = f;
  unsigned r = x.u + 0x7fffu + ((x.u >> 16) & 1u);
  return (unsigned short)(r >> 16);
}

// ---------------- init: zero H/ctr region, out=-1e9, bias interleave -------
__global__ __launch_bounds__(256) void init_kernel(float* __restrict__ ws,
                                                   float* __restrict__ out,
                                                   const float* __restrict__ bf,
                                                   const float* __restrict__ bb,
                                                   int full) {
  int idx = blockIdx.x * 256 + threadIdx.x;
  if (idx < 393216) ws[idx] = 0.f;
  if (idx < BB * 2 * HD) out[idx] = NEGV;
  if (full && idx < 2048) {
    int dir = idx >> 10, jg = idx & 1023, j = jg >> 2, g = jg & 3;
    ws[OFF_B2 + idx] = (dir ? bb : bf)[g * HD + j];
  }
}

// ---------------- prep: transpose W_hh -> [dir][k][j*4+g] (fp32) -----------
__global__ __launch_bounds__(256) void prep_whh(const float* __restrict__ wf,
                                                const float* __restrict__ wb,
                                                float* __restrict__ ws) {
  int o = blockIdx.x * 256 + threadIdx.x;  // < 524288
  int dir = o >> 18, r = o & 262143, k = r >> 10, jg = r & 1023;
  int j = jg >> 2, g = jg & 3;
  const float* W = dir ? wb : wf;
  ws[OFF_WHH + o] = W[(size_t)((g << 8) + j) * HD + k];
}

// ---------------- prep: W_ih -> bf16 [n=dir*1024+j*4+g][k(320 pad)] --------
__global__ __launch_bounds__(256) void prep_wihbf(const float* __restrict__ wf,
                                                  const float* __restrict__ wb,
                                                  float* __restrict__ ws) {
  int n = blockIdx.x;  // 0..2047
  int dir = n >> 10, jg = n & 1023, j = jg >> 2, g = jg & 3;
  const float* W = dir ? wb : wf;
  unsigned short* dst = (unsigned short*)(ws + OFF_WIHB) + (size_t)n * 320;
  for (int k = threadIdx.x; k < 320; k += 256) {
    float v = (k < EE) ? W[(size_t)((g << 8) + j) * EE + k] : 0.f;
    dst[k] = f2bf(v);
  }
}

// ---------------- Zx = X @ WihT via bf16 MFMA 32x32x16 ---------------------
// block 256 thr = 4 waves (2m x 2n), tile 64m x 128n, K-chunks of 64 (5).
// LDS tiles [row][64 k] bf16, 16B-chunk XOR swizzle: g' = g ^ (row&7).
__global__ __launch_bounds__(256) void zx_mfma(const int* __restrict__ tok,
                                               const float* __restrict__ emb,
                                               float* __restrict__ ws) {
  __shared__ __align__(16) unsigned short a_sm[64 * 64];
  __shared__ __align__(16) unsigned short b_sm[128 * 64];
  const int tid = threadIdx.x;
  const int m0 = blockIdx.x * 64;
  const int n0 = blockIdx.y * 128;
  const unsigned short* wihb = (const unsigned short*)(ws + OFF_WIHB);
  float* zx = ws + OFF_ZX;
  const int lane = tid & 63;
  const int wv = tid >> 6;
  const int wm = wv >> 1, wn = wv & 1;

  f32x16 acc0, acc1;
#pragma unroll
  for (int i = 0; i < 16; ++i) { acc0[i] = 0.f; acc1[i] = 0.f; }

  // A staging: row = tid>>2 (64 rows), k-quarter = tid&3 (16 elems)
  const int sm_row = tid >> 2;
  const int sq = tid & 3;
  const int tokv = tok[m0 + sm_row];
  const float* er = emb + (size_t)tokv * EE;
  // B staging: n = tid>>1 (128), k-half = tid&1 (32 elems)
  const int bn = tid >> 1;
  const int bq = tid & 1;
  const unsigned short* bsrc = wihb + (size_t)(n0 + bn) * 320 + bq * 32;

  const int fm = wm * 32 + (lane & 31);   // A row for frags
  const int koc = lane >> 5;              // k-octet selector
  const int fnb = wn * 64 + (lane & 31);  // B col base

  for (int kc = 0; kc < 5; ++kc) {
    const int k0 = kc * 64;
    // ---- stage A (fp32 -> bf16) ----
    {
      union { unsigned short u[8]; uint4 v; } pk;
#pragma unroll
      for (int c = 0; c < 2; ++c) {
#pragma unroll
        for (int e = 0; e < 8; ++e) {
          int k = k0 + sq * 16 + c * 8 + e;
          pk.u[e] = (k < EE) ? f2bf(er[k]) : (unsigned short)0;
        }
        int g = sq * 2 + c;
        int gs = g ^ (sm_row & 7);
        *(uint4*)&a_sm[sm_row * 64 + gs * 8] = pk.v;
      }
    }
    // ---- stage B (bf16 copy) ----
    {
      const unsigned short* s = bsrc + k0;
#pragma unroll
      for (int c = 0; c < 4; ++c) {
        int g = bq * 4 + c;
        int gs = g ^ (bn & 7);
        *(uint4*)&b_sm[bn * 64 + gs * 8] = *(const uint4*)(s + c * 8);
      }
    }
    __syncthreads();
    // ---- fragments + MFMA ----
    bf16x8 afr[4];
#pragma unroll
    for (int ks = 0; ks < 4; ++ks) {
      int gs = (ks * 2 + koc) ^ (fm & 7);
      afr[ks] = *(const bf16x8*)&a_sm[fm * 64 + gs * 8];
    }
#pragma unroll
    for (int nf = 0; nf < 2; ++nf) {
      int n = fnb + nf * 32;
#pragma unroll
      for (int ks = 0; ks < 4; ++ks) {
        int gs = (ks * 2 + koc) ^ (n & 7);
        bf16x8 bfr = *(const bf16x8*)&b_sm[n * 64 + gs * 8];
        if (nf == 0)
          acc0 = __builtin_amdgcn_mfma_f32_32x32x16_bf16(afr[ks], bfr, acc0, 0, 0, 0);
        else
          acc1 = __builtin_amdgcn_mfma_f32_32x32x16_bf16(afr[ks], bfr, acc1, 0, 0, 0);
      }
    }
    __syncthreads();
  }
  // ---- writeout: D row=(r&3)+8*(r>>2)+4*(lane>>5), col=lane&31 (m74) ----
#pragma unroll
  for (int nf = 0; nf < 2; ++nf) {
#pragma unroll
    for (int r = 0; r < 16; ++r) {
      float v = (nf == 0) ? acc0[r] : acc1[r];
      int row = (r & 3) + 8 * (r >> 2) + 4 * (lane >> 5);
      int m = m0 + wm * 32 + row;
      int n = n0 + wn * 64 + nf * 32 + (lane & 31);
      zx[(size_t)m * 2048 + n] = v;
    }
  }
}

// ---------------- persistent recurrence: W register-stationary -------------
// grid = (32 bgroup, 4 slice, 2 dir) x 512 threads, 1 block/CU.
// Barrier: padded per-chain counters (128 B), per-wave independent spin.
__global__ __launch_bounds__(512, 2) void lstm_persist(
    const int* __restrict__ lens, float* __restrict__ ws,
    float* __restrict__ out) {
  const int g = blockIdx.x;      // 0..31
  const int slice = blockIdx.y;  // 0..3
  const int dir = blockIdx.z;    // 0..1
  const int tid = threadIdx.x;
  const int wv = tid >> 6;
  const int ln = tid & 63;

  __shared__ float h_sm[8][256];
  __shared__ float red_sm[8][2048];

  // W slice into registers: w[k] = Whh_t[dir][wv*32+k][slice*256 + ln*4 ..+3]
  float4 w[32];
  {
    const float* wp = ws + OFF_WHH + (size_t)dir * 262144 +
                      (size_t)(wv * 32) * 1024 + slice * 256 + ln * 4;
#pragma unroll
    for (int k = 0; k < 32; ++k) w[k] = *(const float4*)(wp + (size_t)k * 1024);
  }
  const int brow = g * 8 + wv;
  const int len = lens[brow];
  const float4 bias =
      *(const float4*)(ws + OFF_B2 + dir * 1024 + slice * 256 + ln * 4);
  float c = 0.f, omax = NEGV;
  unsigned int* ctr =
      (unsigned int*)(ws + OFF_CTR) + (size_t)(dir * 32 + g) * 32;
  const float* zx = ws + OFF_ZX;
  float* hb = ws + OFF_H;  // [2 buf][2 dir][256 b][256 j]
  const int j = slice * 64 + ln;
  const size_t zxbase = (size_t)brow * TT;
  const int zxoff = dir * 1024 + slice * 256 + ln * 4;

  float4 zx4 = *(const float4*)(zx + (zxbase + (dir ? TT - 1 : 0)) * 2048 + zxoff);

  for (int s = 0; s < TT; ++s) {
    const int t = dir ? (TT - 1 - s) : s;
    // stage h(s) from buf s&1 via coherent point loads (2x u64 per thread)
    {
      const float* src =
          hb + (size_t)((((s & 1) * 2 + dir) * 256) + g * 8 + wv) * 256 + ln * 4;
      const unsigned long long* s8 = (const unsigned long long*)src;
      unsigned long long u0 =
          __hip_atomic_load(s8 + 0, __ATOMIC_RELAXED, __HIP_MEMORY_SCOPE_AGENT);
      unsigned long long u1 =
          __hip_atomic_load(s8 + 1, __ATOMIC_RELAXED, __HIP_MEMORY_SCOPE_AGENT);
      float2 f0, f1;
      __builtin_memcpy(&f0, &u0, 8);
      __builtin_memcpy(&f1, &u1, 8);
      h_sm[wv][ln * 4 + 0] = f0.x;
      h_sm[wv][ln * 4 + 1] = f0.y;
      h_sm[wv][ln * 4 + 2] = f1.x;
      h_sm[wv][ln * 4 + 3] = f1.y;
    }
    __syncthreads();
    // FMA over k window [wv*32, wv*32+32)
    float4 acc[8];
#pragma unroll
    for (int r = 0; r < 8; ++r) acc[r] = make_float4(0.f, 0.f, 0.f, 0.f);
#pragma unroll
    for (int kq = 0; kq < 8; ++kq) {
      float4 h4[8];
#pragma unroll
      for (int r = 0; r < 8; ++r)
        h4[r] = *(const float4*)&h_sm[r][wv * 32 + kq * 4];
#pragma unroll
      for (int kk = 0; kk < 4; ++kk) {
#pragma unroll
        for (int r = 0; r < 8; ++r) {
          float hv = kk == 0 ? h4[r].x : kk == 1 ? h4[r].y
                     : kk == 2 ? h4[r].z : h4[r].w;
          float4 wk = w[kq * 4 + kk];
          acc[r].x += hv * wk.x; acc[r].y += hv * wk.y;
          acc[r].z += hv * wk.z; acc[r].w += hv * wk.w;
        }
      }
    }
#pragma unroll
    for (int r = 0; r < 8; ++r)
      *(float4*)&red_sm[wv][r * 256 + ln * 4] = acc[r];
    __syncthreads();
    // reduce 8 ksegs for (row=wv, quad=ln)
    float4 z = make_float4(0.f, 0.f, 0.f, 0.f);
#pragma unroll
    for (int ks = 0; ks < 8; ++ks) {
      float4 p = *(const float4*)&red_sm[ks][wv * 256 + ln * 4];
      z.x += p.x; z.y += p.y; z.z += p.z; z.w += p.w;
    }
    float h_old = h_sm[wv][j];
    float h_out = h_old;
    if (t < len) {
      float ig = sigf(z.x + zx4.x + bias.x);
      float fg = sigf(z.y + zx4.y + bias.y);
      float gg = tanhfast(z.z + zx4.z + bias.z);
      float og = sigf(z.w + zx4.w + bias.w);
      c = fg * c + ig * gg;
      float hn = og * tanhfast(c);
      h_out = hn;
      omax = fmaxf(omax, hn);
    }
    if (s < TT - 1) {
      float* dst =
          hb + (size_t)(((((s + 1) & 1) * 2 + dir) * 256) + brow) * 256 + j;
      __hip_atomic_store(dst, h_out, __ATOMIC_RELAXED,
                         __HIP_MEMORY_SCOPE_AGENT);
      // prefetch next step's zx while stores drain / flag propagates
      const int tn = dir ? (TT - 2 - s) : (s + 1);
      float4 zxn = *(const float4*)(zx + (zxbase + tn) * 2048 + zxoff);
      asm volatile("s_waitcnt vmcnt(0)" ::: "memory");
      __syncthreads();  // all waves drained their h stores
      if (tid == 0) {
        __hip_atomic_fetch_add(ctr, 1u, __ATOMIC_RELAXED,
                               __HIP_MEMORY_SCOPE_AGENT);
      }
      const unsigned int target = 4u * (unsigned)(s + 1);
      while (__hip_atomic_load(ctr, __ATOMIC_RELAXED,
                               __HIP_MEMORY_SCOPE_AGENT) < target) {
      }
      asm volatile("" ::: "memory");  // no hoisting h loads above the spin
      zx4 = zxn;
    }
  }
  out[(size_t)brow * (2 * HD) + dir * HD + j] = omax;
}

// ---------------- fallback (round-1 fused step) if ws too small ------------
__global__ __launch_bounds__(256) void step_fused(
    const int* __restrict__ tok, const int* __restrict__ lens,
    const float* __restrict__ emb,
    const float* __restrict__ wih_f, const float* __restrict__ whh_f,
    const float* __restrict__ bias_f,
    const float* __restrict__ wih_b, const float* __restrict__ whh_b,
    const float* __restrict__ bias_b,
    float* __restrict__ ws, float* __restrict__ out, int s) {
  const int tid = threadIdx.x;
  const int jt = blockIdx.x, bt = blockIdx.y, dir = blockIdx.z;
  const int j0 = jt * 32, b0g = bt * 16;
  const int t = (dir == 0) ? s : (TT - 1 - s);
  const float* Wih = dir ? wih_b : wih_f;
  const float* Whh = dir ? whh_b : whh_f;
  const float* bias = dir ? bias_b : bias_f;
  const float* hcur = ws + OFF_H + (size_t)((s & 1) * 2 + dir) * BB * HD;
  float* hnxt = ws + OFF_H + (size_t)(((s + 1) & 1) * 2 + dir) * BB * HD;
  float* cbuf = ws + OFF_C + (size_t)dir * BB * HD;

  __shared__ float a_sm[16][64];
  __shared__ float w_sm[64][132];
  __shared__ float z_sm[16][132];

  const int cg = tid & 31, bg = tid >> 5;
  float acc[2][4] = {{0.f, 0.f, 0.f, 0.f}, {0.f, 0.f, 0.f, 0.f}};

  for (int phase = 0; phase < 2; ++phase) {
    const float* W = phase ? Whh : Wih;
    const int K = phase ? HD : EE;
    for (int k0 = 0; k0 < K; k0 += 64) {
      const int klen = (K - k0) < 64 ? (K - k0) : 64;
      {
        int bl = tid >> 4, kk4 = tid & 15;
        if (kk4 * 4 < klen) {
          const float* src;
          if (phase == 0) {
            int tk = tok[(b0g + bl) * TT + t];
            src = emb + (size_t)tk * EE + k0 + kk4 * 4;
          } else {
            src = hcur + (size_t)(b0g + bl) * HD + k0 + kk4 * 4;
          }
          *(float4*)&a_sm[bl][kk4 * 4] = *(const float4*)src;
        }
      }
      for (int i = 0; i < 8; ++i) {
        int e = i * 256 + tid;
        int col = e >> 4, kk4 = e & 15;
        if (kk4 * 4 < klen) {
          int gcol = ((col >> 5) * HD) + j0 + (col & 31);
          float4 v = *(const float4*)(W + (size_t)gcol * K + k0 + kk4 * 4);
          w_sm[kk4 * 4 + 0][col] = v.x;
          w_sm[kk4 * 4 + 1][col] = v.y;
          w_sm[kk4 * 4 + 2][col] = v.z;
          w_sm[kk4 * 4 + 3][col] = v.w;
        }
      }
      __syncthreads();
      for (int k = 0; k < klen; ++k) {
        float a0 = a_sm[bg * 2 + 0][k];
        float a1 = a_sm[bg * 2 + 1][k];
        float4 w = *(const float4*)&w_sm[k][cg * 4];
        acc[0][0] += a0 * w.x; acc[0][1] += a0 * w.y;
        acc[0][2] += a0 * w.z; acc[0][3] += a0 * w.w;
        acc[1][0] += a1 * w.x; acc[1][1] += a1 * w.y;
        acc[1][2] += a1 * w.z; acc[1][3] += a1 * w.w;
      }
      __syncthreads();
    }
  }
  *(float4*)&z_sm[bg * 2 + 0][cg * 4] =
      make_float4(acc[0][0], acc[0][1], acc[0][2], acc[0][3]);
  *(float4*)&z_sm[bg * 2 + 1][cg * 4] =
      make_float4(acc[1][0], acc[1][1], acc[1][2], acc[1][3]);
  __syncthreads();
  for (int pi = 0; pi < 2; ++pi) {
    int p = pi * 256 + tid;
    int bl = p >> 5, jl = p & 31;
    int bglob = b0g + bl, jglob = j0 + jl;
    bool valid = t < lens[bglob];
    float h_old = hcur[(size_t)bglob * HD + jglob];
    float h_out = h_old;
    if (valid) {
      float zi = z_sm[bl][0 + jl] + bias[0 * HD + jglob];
      float zf = z_sm[bl][32 + jl] + bias[1 * HD + jglob];
      float zg = z_sm[bl][64 + jl] + bias[2 * HD + jglob];
      float zo = z_sm[bl][96 + jl] + bias[3 * HD + jglob];
      float ig = sigf(zi), fg = sigf(zf), gg = tanhf(zg), og = sigf(zo);
      float c_old = cbuf[(size_t)bglob * HD + jglob];
      float c_new = fg * c_old + ig * gg;
      float h_new = og * tanhf(c_new);
      cbuf[(size_t)bglob * HD + jglob] = c_new;
      h_out = h_new;
      float* op = out + (size_t)bglob * (2 * HD) + dir * HD + jglob;
      *op = fmaxf(*op, h_new);
    }
    hnxt[(size_t)bglob * HD + jglob] = h_out;
  }
}

extern "C" void kernel_launch(void* const* d_in, const int* in_sizes, int n_in,
                              void* d_out, int out_size, void* d_ws,
                              size_t ws_size, hipStream_t stream) {
  const int* tok = (const int*)d_in[0];
  const int* lens = (const int*)d_in[1];
  const float* emb = (const float*)d_in[2];
  const float* wih_f = (const float*)d_in[3];
  const float* whh_f = (const float*)d_in[4];
  const float* b_f = (const float*)d_in[5];
  const float* wih_b = (const float*)d_in[6];
  const float* whh_b = (const float*)d_in[7];
  const float* b_b = (const float*)d_in[8];
  float* out = (float*)d_out;
  float* ws = (float*)d_ws;

  const bool full = ws_size >= WS_FULL_BYTES;
  hipLaunchKernelGGL(init_kernel, dim3(1536), dim3(256), 0, stream, ws, out,
                     b_f, b_b, full ? 1 : 0);
  if (full) {
    hipLaunchKernelGGL(prep_whh, dim3(2048), dim3(256), 0, stream, whh_f,
                       whh_b, ws);
    hipLaunchKernelGGL(prep_wihbf, dim3(2048), dim3(256), 0, stream, wih_f,
                       wih_b, ws);
    hipLaunchKernelGGL(zx_mfma, dim3(256, 16), dim3(256), 0, stream, tok, emb,
                       ws);
    hipLaunchKernelGGL(lstm_persist, dim3(32, 4, 2), dim3(512), 0, stream,
                       lens, ws, out);
  } else {
    for (int s = 0; s < TT; ++s) {
      hipLaunchKernelGGL(step_fused, dim3(8, 16, 2), dim3(256), 0, stream, tok,
                         lens, emb, wih_f, whh_f, b_f, wih_b, whh_b, b_b, ws,
                         out, s);
    }
  }
}